// Round 10
// baseline (1662.021 us; speedup 1.0000x reference)
//
#include <hip/hip_runtime.h>
#include <math.h>

#define Bq 8
#define Lq 65536
#define Hq 32
#define Nq 8
#define DEPq 4
#define LCq 64
#define NCq (Lq/LCq)     // 1024 chunks per b
#define GRPq 32
#define NGq  (NCq/GRPq)  // 32 groups
#define PAD 36           // LDS row pitch (floats): 144B, 16B-aligned, 2-way max on row reads

// ---------------- conditioning MLP + FiLM ----------------
__global__ void k_cond_film(const float* __restrict__ prm,
                            const float* __restrict__ W1, const float* __restrict__ b1,
                            const float* __restrict__ W2, const float* __restrict__ b2,
                            const float* __restrict__ W3, const float* __restrict__ b3,
                            const float* __restrict__ filmW, const float* __restrict__ filmB,
                            float* __restrict__ film /* [DEP][B][2H] */)
{
    __shared__ float cond[Bq][32];
    int tid = threadIdx.x, d = blockIdx.x;
    if (tid < Bq) {
        float p0 = prm[tid*2+0], p1 = prm[tid*2+1];
        float c1[16];
        #pragma unroll
        for (int i=0;i<16;i++){ float v = W1[i*2+0]*p0 + W1[i*2+1]*p1 + b1[i]; c1[i]=v>0.f?v:0.f; }
        float c2[32];
        #pragma unroll
        for (int i=0;i<32;i++){ float a=b2[i];
            #pragma unroll
            for(int j=0;j<16;j++) a = fmaf(W2[i*16+j], c1[j], a);
            c2[i]=a>0.f?a:0.f; }
        #pragma unroll
        for (int i=0;i<32;i++){ float a=b3[i];
            #pragma unroll
            for(int j=0;j<32;j++) a = fmaf(W3[i*32+j], c2[j], a);
            cond[tid][i]=a>0.f?a:0.f; }
    }
    __syncthreads();
    int b = tid>>6, k = tid&63;
    float a = filmB[d*2*Hq + k];
    #pragma unroll
    for (int j=0;j<32;j++) a = fmaf(cond[b][j], filmW[(d*2*Hq + k)*32 + j], a);
    film[(d*Bq + b)*2*Hq + k] = a;
}

// ---------------- S4D derived params (f64 derivation, f32 tables) ----------------
__global__ void k_s4params(const float* __restrict__ log_dt, const float* __restrict__ logAre,
                           const float* __restrict__ Aim_, const float* __restrict__ Cre_,
                           const float* __restrict__ Cim_,
                           float* __restrict__ pw, float* __restrict__ pc2,
                           float* __restrict__ pwL, float* __restrict__ pwG)
{
    int idx = threadIdx.x; // DEP*H*N = 1024
    int d = idx/(Hq*Nq); int h = (idx/Nq)%Hq;
    double dt = exp((double)log_dt[d*Hq+h]);
    double Are = -exp((double)logAre[idx]);
    double Aim = (double)Aim_[idx];
    double dar = dt*Are, dai = dt*Aim;
    double er = exp(dar);
    double wr = er*cos(dai), wi = er*sin(dai);
    double em1r = wr - 1.0, em1i = wi;
    double den = Are*Are + Aim*Aim;
    double qr = (em1r*Are + em1i*Aim)/den;
    double qi = (em1i*Are - em1r*Aim)/den;
    double Cr = (double)Cre_[idx], Ci = (double)Cim_[idx];
    double eL = exp(dar*(double)LCq);
    double eG = exp(dar*(double)(LCq*GRPq));
    pw [idx*2+0]=(float)wr;  pw [idx*2+1]=(float)wi;
    pc2[idx*2+0]=(float)(2.0*(Cr*qr - Ci*qi)); pc2[idx*2+1]=(float)(2.0*(Cr*qi + Ci*qr));
    pwL[idx*2+0]=(float)(eL*cos(dai*(double)LCq));        pwL[idx*2+1]=(float)(eL*sin(dai*(double)LCq));
    pwG[idx*2+0]=(float)(eG*cos(dai*(double)(LCq*GRPq))); pwG[idx*2+1]=(float)(eG*sin(dai*(double)(LCq*GRPq)));
}

// ---------------- premix for depth 0 ----------------
__global__ void k_premix(const float* __restrict__ linW, const float* __restrict__ linB,
                         const float* __restrict__ eW, const float* __restrict__ eb,
                         float* __restrict__ ab0)
{
    int g = threadIdx.x;  // 32
    float a = 0.f, be = linB[g];
    #pragma unroll
    for (int h=0;h<Hq;h++){ a = fmaf(linW[g*Hq+h], eW[h], a); be = fmaf(linW[g*Hq+h], eb[h], be); }
    ab0[g] = a; ab0[32+g] = be;
}

// ---------------- k_first: u0 = relu(x*al+be), chunk-local scan_0 -> sloc ----------------
__global__ __launch_bounds__(256) void k_first(
    const float* __restrict__ x, const float* __restrict__ ab0,
    const float* __restrict__ pw, float* __restrict__ sloc)
{
    __shared__ float xs[LCq];
    int tid = threadIdx.x;
    int cg = blockIdx.x; int b = cg >> 10, c = cg & (NCq-1);
    if (tid < LCq) xs[tid] = x[(size_t)b*Lq + (size_t)c*LCq + tid];
    __syncthreads();
    int ch = tid >> 3, m = tid & 7;
    float wr = pw[(ch*Nq+m)*2], wi = pw[(ch*Nq+m)*2+1];
    float al = ab0[ch], be = ab0[32+ch];
    float sr = 0.f, si = 0.f;
    #pragma unroll 4
    for (int j=0;j<LCq;j++){
        float u = fmaf(xs[j], al, be); u = u>0.f?u:0.f;
        float nr = fmaf(wr, sr, fmaf(-wi, si, u));
        float ni = fmaf(wr, si, wi*sr);
        sr=nr; si=ni;
    }
    size_t sb = ((size_t)(b*NCq + c)*Hq + ch)*16;
    sloc[sb+m] = sr; sloc[sb+8+m] = si;
}

// ---------------- pass2: two-level prefix over chunks, block per (b,h) ----------------
__global__ __launch_bounds__(256) void k_pass2(const float* __restrict__ sloc,
    const float* __restrict__ pwL, const float* __restrict__ pwG, float* __restrict__ sini)
{
    __shared__ float aux[NGq*Nq*2];
    int bid = blockIdx.x; int b = bid >> 5, h = bid & 31;
    int tid = threadIdx.x;
    int n = tid & 7, g2 = tid >> 3;
    float wLr = pwL[(h*Nq+n)*2], wLi = pwL[(h*Nq+n)*2+1];
    float sr=0.f, si=0.f;
    for (int k=0;k<GRPq;k++){
        size_t off = ((size_t)(b*NCq + g2*GRPq+k)*Hq + h)*16;
        float lr = sloc[off+n], li = sloc[off+8+n];
        float nr = fmaf(wLr,sr, fmaf(-wLi,si, lr));
        float ni = fmaf(wLr,si, fmaf( wLi,sr, li));
        sr=nr; si=ni;
    }
    aux[(g2*8+n)*2+0]=sr; aux[(g2*8+n)*2+1]=si;
    __syncthreads();
    if (tid < 8) {
        float wGr = pwG[(h*Nq+tid)*2], wGi = pwG[(h*Nq+tid)*2+1];
        float pr=0.f, pi=0.f;
        for (int g=0; g<NGq; g++){
            float er_ = aux[(g*8+tid)*2+0], ei_ = aux[(g*8+tid)*2+1];
            aux[(g*8+tid)*2+0]=pr; aux[(g*8+tid)*2+1]=pi;
            float nr = fmaf(wGr,pr, fmaf(-wGi,pi, er_));
            float ni = fmaf(wGr,pi, fmaf( wGi,pr, ei_));
            pr=nr; pi=ni;
        }
    }
    __syncthreads();
    sr = aux[(g2*8+n)*2+0]; si = aux[(g2*8+n)*2+1];
    for (int k=0;k<GRPq;k++){
        size_t off = ((size_t)(b*NCq + g2*GRPq+k)*Hq + h)*16;
        float lr = sloc[off+n], li = sloc[off+8+n];
        sini[off+n] = sr; sini[off+8+n] = si;
        float nr = fmaf(wLr,sr, fmaf(-wLi,si, lr));
        float ni = fmaf(wLr,si, fmaf( wLi,sr, li));
        sr=nr; si=ni;
    }
}

// 32-wide mix for one row from LDS (padded rows -> 2-way max conflicts)
__device__ __forceinline__ void mix_row(const float* row, const float* __restrict__ W,
                                        const float* __restrict__ Bv, int q, float o[8])
{
    float hrow[Hq];
    #pragma unroll
    for (int k=0;k<8;k++) ((float4*)hrow)[k] = ((const float4*)row)[k];
    #pragma unroll
    for (int g8=0; g8<8; g8++){
        int g = q*8+g8;
        const float4* Wr = (const float4*)(W + g*Hq);
        float a0=0.f,a1=0.f,a2=0.f,a3=0.f;
        #pragma unroll
        for (int k=0;k<8;k++){
            float4 w4 = Wr[k];
            a0 = fmaf(w4.x, hrow[4*k+0], a0);
            a1 = fmaf(w4.y, hrow[4*k+1], a1);
            a2 = fmaf(w4.z, hrow[4*k+2], a2);
            a3 = fmaf(w4.w, hrow[4*k+3], a3);
        }
        float u = Bv[g] + ((a0+a1)+(a2+a3));
        o[g8] = u>0.f?u:0.f;
    }
}

// ---------------- k_main(d<3): phase-split, padded tiles, separate R/W arrays ----------------
__global__ __launch_bounds__(256) void k_main(
    const float* __restrict__ x, float* __restrict__ hbuf, int first,
    const float* __restrict__ eW, const float* __restrict__ eb,
    const float* __restrict__ ab0,
    const float* __restrict__ linW_d, const float* __restrict__ linB_d,
    const float* __restrict__ linW_n, const float* __restrict__ linB_n,
    const float* __restrict__ pw_d, const float* __restrict__ pc2_d,
    const float* __restrict__ pw_n,
    const float* __restrict__ sini, float* __restrict__ sloc,
    const float* __restrict__ Dskip, const float* __restrict__ film,
    const float* __restrict__ resw)
{
    __shared__ float htile[LCq][PAD];
    __shared__ float utile[LCq][PAD];
    __shared__ float ytile[LCq][PAD];
    __shared__ float xs[LCq];
    int tid = threadIdx.x;
    int cg = blockIdx.x; int b = cg >> 10, c = cg & (NCq-1);
    size_t recbase = ((size_t)b*Lq + (size_t)c*LCq)*Hq;
    int j = tid >> 2, q = tid & 3;
    int ch = tid >> 3, m = tid & 7;
    // ---- A: stage
    if (first) {
        if (tid < LCq) xs[tid] = x[(size_t)b*Lq + (size_t)c*LCq + tid];
    } else {
        const float4* src = (const float4*)(hbuf + recbase);
        ((float4*)&htile[tid>>3][0])[tid&7] = src[tid];
        int i2 = tid+256;
        ((float4*)&htile[i2>>3][0])[i2&7] = src[i2];
    }
    __syncthreads();
    // ---- A1: mix_d -> utile (first: also materialize h0 into htile)
    if (first) {
        float xv = xs[j];
        #pragma unroll
        for (int g8=0; g8<8; g8++){
            int g = q*8+g8;
            float u = fmaf(xv, ab0[g], ab0[32+g]);
            utile[j][g] = u>0.f?u:0.f;
            htile[j][g] = fmaf(xv, eW[g], eb[g]);
        }
    } else {
        float o[8];
        mix_row(&htile[j][0], linW_d, linB_d, q, o);
        ((float4*)&utile[j][0])[q*2+0] = make_float4(o[0],o[1],o[2],o[3]);
        ((float4*)&utile[j][0])[q*2+1] = make_float4(o[4],o[5],o[6],o[7]);
    }
    __syncthreads();
    // ---- B: seeded scan_d + film + relu -> ytile (reads utile only, writes ytile only)
    {
        float wr = pw_d[(ch*Nq+m)*2], wi = pw_d[(ch*Nq+m)*2+1];
        float cr = pc2_d[(ch*Nq+m)*2], ci = pc2_d[(ch*Nq+m)*2+1];
        size_t sb = ((size_t)(b*NCq + c)*Hq + ch)*16;
        float sr = sini[sb+m], si = sini[sb+8+m];
        float D  = Dskip[ch];
        float gf = film[b*2*Hq + ch], bf = film[b*2*Hq + Hq + ch];
        #pragma unroll 4
        for (int jj=0;jj<LCq;jj++){
            float u = utile[jj][ch];
            float nr = fmaf(wr, sr, fmaf(-wi, si, u));
            float ni = fmaf(wr, si, wi*sr);
            sr=nr; si=ni;
            float y = fmaf(cr, nr, -(ci*ni));
            y += __shfl_xor(y, 1);
            y += __shfl_xor(y, 2);
            y += __shfl_xor(y, 4);
            if (m==0){
                float yt = fmaf(D, u, y);
                yt = fmaf(yt, gf, bf);
                ytile[jj][ch] = yt>0.f?yt:0.f;
            }
        }
    }
    __syncthreads();
    // ---- C: residual -> htile (thread owns its 8 channels of row j exclusively)
    {
        #pragma unroll
        for (int g8=0; g8<8; g8++){
            int g = q*8+g8;
            htile[j][g] = fmaf(resw[g], htile[j][g], ytile[j][g]);
        }
    }
    __syncthreads();
    // ---- C2: coalesced hbuf write + mix_{d+1} -> utile
    {
        float4* dst = (float4*)(hbuf + recbase);
        dst[tid]     = ((const float4*)&htile[tid>>3][0])[tid&7];
        int i2 = tid+256;
        dst[i2]      = ((const float4*)&htile[i2>>3][0])[i2&7];
        float o[8];
        mix_row(&htile[j][0], linW_n, linB_n, q, o);
        ((float4*)&utile[j][0])[q*2+0] = make_float4(o[0],o[1],o[2],o[3]);
        ((float4*)&utile[j][0])[q*2+1] = make_float4(o[4],o[5],o[6],o[7]);
    }
    __syncthreads();
    // ---- D: chunk-local scan_{d+1} -> sloc
    {
        float vr = pw_n[(ch*Nq+m)*2], vi = pw_n[(ch*Nq+m)*2+1];
        float tr=0.f, ti=0.f;
        #pragma unroll 4
        for (int jj=0;jj<LCq;jj++){
            float u = utile[jj][ch];
            float nr = fmaf(vr, tr, fmaf(-vi, ti, u));
            float ni = fmaf(vr, ti, vi*tr);
            tr=nr; ti=ni;
        }
        size_t sb = ((size_t)(b*NCq + c)*Hq + ch)*16;
        sloc[sb+m] = tr; sloc[sb+8+m] = ti;
    }
}

// ---------------- k_last (d=3): stage + mix + scan + film + residual + contract + tanh ----------------
__global__ __launch_bounds__(256) void k_last(
    const float* __restrict__ x, const float* __restrict__ hbuf,
    const float* __restrict__ linW_d, const float* __restrict__ linB_d,
    const float* __restrict__ pw_d, const float* __restrict__ pc2_d,
    const float* __restrict__ sini,
    const float* __restrict__ Dskip, const float* __restrict__ film,
    const float* __restrict__ resw, const float* __restrict__ cW,
    const float* __restrict__ cb, float* __restrict__ out)
{
    __shared__ float htile[LCq][PAD];
    __shared__ float utile[LCq][PAD];
    __shared__ float ytile[LCq][PAD];
    __shared__ float xs[LCq];
    int tid = threadIdx.x;
    int cg = blockIdx.x; int b = cg >> 10, c = cg & (NCq-1);
    size_t recbase = ((size_t)b*Lq + (size_t)c*LCq)*Hq;
    int j = tid >> 2, q = tid & 3;
    int ch = tid >> 3, m = tid & 7;
    {
        const float4* src = (const float4*)(hbuf + recbase);
        ((float4*)&htile[tid>>3][0])[tid&7] = src[tid];
        int i2 = tid+256;
        ((float4*)&htile[i2>>3][0])[i2&7] = src[i2];
        if (tid < LCq) xs[tid] = x[(size_t)b*Lq + (size_t)c*LCq + tid];
    }
    __syncthreads();
    {
        float o[8];
        mix_row(&htile[j][0], linW_d, linB_d, q, o);
        ((float4*)&utile[j][0])[q*2+0] = make_float4(o[0],o[1],o[2],o[3]);
        ((float4*)&utile[j][0])[q*2+1] = make_float4(o[4],o[5],o[6],o[7]);
    }
    __syncthreads();
    {
        float wr = pw_d[(ch*Nq+m)*2], wi = pw_d[(ch*Nq+m)*2+1];
        float cr = pc2_d[(ch*Nq+m)*2], ci = pc2_d[(ch*Nq+m)*2+1];
        size_t sb = ((size_t)(b*NCq + c)*Hq + ch)*16;
        float sr = sini[sb+m], si = sini[sb+8+m];
        float D  = Dskip[ch];
        float gf = film[b*2*Hq + ch], bf = film[b*2*Hq + Hq + ch];
        #pragma unroll 4
        for (int jj=0;jj<LCq;jj++){
            float u = utile[jj][ch];
            float nr = fmaf(wr, sr, fmaf(-wi, si, u));
            float ni = fmaf(wr, si, wi*sr);
            sr=nr; si=ni;
            float y = fmaf(cr, nr, -(ci*ni));
            y += __shfl_xor(y, 1);
            y += __shfl_xor(y, 2);
            y += __shfl_xor(y, 4);
            if (m==0){
                float yt = fmaf(D, u, y);
                yt = fmaf(yt, gf, bf);
                ytile[jj][ch] = yt>0.f?yt:0.f;
            }
        }
    }
    __syncthreads();
    {
        float part = 0.f;
        #pragma unroll
        for (int g8=0; g8<8; g8++){
            int g = q*8+g8;
            float hn = fmaf(resw[g], htile[j][g], ytile[j][g]);
            part = fmaf(cW[g], hn, part);
        }
        part += __shfl_xor(part, 1);
        part += __shfl_xor(part, 2);
        if (q == 0)
            out[(size_t)b*Lq + (size_t)c*LCq + j] = xs[j]*tanhf(part + cb[0]);
    }
}

// ---------------- diagnostic flag ----------------
__global__ void k_flag(float* __restrict__ out, int code) { out[0] = (float)code; }

extern "C" void kernel_launch(void* const* d_in, const int* in_sizes, int n_in,
                              void* d_out, int out_size, void* d_ws, size_t ws_size,
                              hipStream_t stream)
{
    const float* x    = (const float*)d_in[0];
    const float* prm  = (const float*)d_in[1];
    const float* W1   = (const float*)d_in[2];  const float* b1 = (const float*)d_in[3];
    const float* W2   = (const float*)d_in[4];  const float* b2 = (const float*)d_in[5];
    const float* W3   = (const float*)d_in[6];  const float* b3 = (const float*)d_in[7];
    const float* eW   = (const float*)d_in[8];  const float* eb = (const float*)d_in[9];
    const float* linW = (const float*)d_in[10]; const float* linB = (const float*)d_in[11];
    const float* log_dt = (const float*)d_in[12]; const float* logAre = (const float*)d_in[13];
    const float* Aim  = (const float*)d_in[14]; const float* Cre = (const float*)d_in[15];
    const float* Cim  = (const float*)d_in[16]; const float* Dskip = (const float*)d_in[17];
    const float* filmW= (const float*)d_in[18]; const float* filmB = (const float*)d_in[19];
    const float* resw = (const float*)d_in[20]; const float* cW = (const float*)d_in[21];
    const float* cb   = (const float*)d_in[22];

    float* sloc = (float*)d_ws;                                    // B*NC*H*16 = 4194304 f
    float* sini = sloc + (size_t)Bq*NCq*Hq*16;                     // 4194304 f
    float* pw   = sini + (size_t)Bq*NCq*Hq*16;                     // 2048 f
    float* pc2  = pw  + DEPq*Hq*Nq*2;                              // 2048 f
    float* pwL  = pc2 + DEPq*Hq*Nq*2;                              // 2048 f
    float* pwG  = pwL + DEPq*Hq*Nq*2;                              // 2048 f
    float* film = pwG + DEPq*Hq*Nq*2;                              // 2048 f
    float* ab0  = film + DEPq*Bq*2*Hq;                             // 64 f
    float* hbuf = ab0 + 64;                                        // B*L*H = 16777216 f
    float* out  = (float*)d_out;
    size_t ws_needed = (char*)(hbuf + (size_t)Bq*Lq*Hq) - (char*)d_ws;

    const int scan_grid = Bq*NCq;   // 8192 blocks

    hipLaunchKernelGGL(k_cond_film, dim3(DEPq), dim3(512), 0, stream,
                       prm,W1,b1,W2,b2,W3,b3,filmW,filmB,film);
    hipLaunchKernelGGL(k_s4params, dim3(1), dim3(DEPq*Hq*Nq), 0, stream,
                       log_dt,logAre,Aim,Cre,Cim,pw,pc2,pwL,pwG);
    hipLaunchKernelGGL(k_premix, dim3(1), dim3(Hq), 0, stream, linW, linB, eW, eb, ab0);
    hipLaunchKernelGGL(k_first, dim3(scan_grid), dim3(256), 0, stream, x, ab0, pw, sloc);
    for (int d=0; d<DEPq; d++){
        hipLaunchKernelGGL(k_pass2, dim3(Bq*Hq), dim3(256), 0, stream,
                           sloc, pwL + d*Hq*Nq*2, pwG + d*Hq*Nq*2, sini);
        if (d < DEPq-1) {
            hipLaunchKernelGGL(k_main, dim3(scan_grid), dim3(256), 0, stream,
                               x, hbuf, (d==0)?1:0, eW, eb, ab0,
                               linW + d*Hq*Hq, linB + d*Hq,
                               linW + (d+1)*Hq*Hq, linB + (d+1)*Hq,
                               pw + d*Hq*Nq*2, pc2 + d*Hq*Nq*2, pw + (d+1)*Hq*Nq*2,
                               sini, sloc,
                               Dskip + d*Hq, film + d*Bq*2*Hq, resw + d*Hq);
        } else {
            hipLaunchKernelGGL(k_last, dim3(scan_grid), dim3(256), 0, stream,
                               x, hbuf,
                               linW + d*Hq*Hq, linB + d*Hq,
                               pw + d*Hq*Nq*2, pc2 + d*Hq*Nq*2,
                               sini,
                               Dskip + d*Hq, film + d*Bq*2*Hq, resw + d*Hq,
                               cW, cb, out);
        }
    }

    static const int expected[23] = {
        Bq*Lq, Bq*2, 32, 16, 512, 32, 1024, 32, Hq, Hq,
        DEPq*Hq*Hq, DEPq*Hq, DEPq*Hq, DEPq*Hq*Nq, DEPq*Hq*Nq, DEPq*Hq*Nq, DEPq*Hq*Nq,
        DEPq*Hq, DEPq*2*Hq*32, DEPq*2*Hq, DEPq*Hq, Hq, 1
    };
    int code = 0;
    if (n_in != 23) code = 99;
    else { for (int i = 0; i < 23; i++) if (in_sizes[i] != expected[i]) { code = 100 + i; break; } }
    if (!code && ws_size < ws_needed) code = 200;
    if (code) hipLaunchKernelGGL(k_flag, dim3(1), dim3(1), 0, stream, out, code);
}

// Round 12
// 934.916 us; speedup vs baseline: 1.7777x; 1.7777x over previous
//
#include <hip/hip_runtime.h>
#include <math.h>

#define Bq 8
#define Lq 65536
#define Hq 32
#define Nq 8
#define DEPq 4
#define LCq 64
#define NCq (Lq/LCq)     // 1024 chunks per b
#define GRPq 32
#define NGq  (NCq/GRPq)  // 32 groups
#define CHB 8            // chunks per k_main block

// ---------------- conditioning MLP + FiLM ----------------
__global__ void k_cond_film(const float* __restrict__ prm,
                            const float* __restrict__ W1, const float* __restrict__ b1,
                            const float* __restrict__ W2, const float* __restrict__ b2,
                            const float* __restrict__ W3, const float* __restrict__ b3,
                            const float* __restrict__ filmW, const float* __restrict__ filmB,
                            float* __restrict__ film /* [DEP][B][2H] */)
{
    __shared__ float cond[Bq][32];
    int tid = threadIdx.x, d = blockIdx.x;
    if (tid < Bq) {
        float p0 = prm[tid*2+0], p1 = prm[tid*2+1];
        float c1[16];
        #pragma unroll
        for (int i=0;i<16;i++){ float v = W1[i*2+0]*p0 + W1[i*2+1]*p1 + b1[i]; c1[i]=v>0.f?v:0.f; }
        float c2[32];
        #pragma unroll
        for (int i=0;i<32;i++){ float a=b2[i];
            #pragma unroll
            for(int j=0;j<16;j++) a = fmaf(W2[i*16+j], c1[j], a);
            c2[i]=a>0.f?a:0.f; }
        #pragma unroll
        for (int i=0;i<32;i++){ float a=b3[i];
            #pragma unroll
            for(int j=0;j<32;j++) a = fmaf(W3[i*32+j], c2[j], a);
            cond[tid][i]=a>0.f?a:0.f; }
    }
    __syncthreads();
    int b = tid>>6, k = tid&63;
    float a = filmB[d*2*Hq + k];
    #pragma unroll
    for (int j=0;j<32;j++) a = fmaf(cond[b][j], filmW[(d*2*Hq + k)*32 + j], a);
    film[(d*Bq + b)*2*Hq + k] = a;
}

// ---------------- S4D derived params ----------------
__global__ void k_s4params(const float* __restrict__ log_dt, const float* __restrict__ logAre,
                           const float* __restrict__ Aim_, const float* __restrict__ Cre_,
                           const float* __restrict__ Cim_,
                           float* __restrict__ pw, float* __restrict__ pc2,
                           float* __restrict__ pwL, float* __restrict__ pwG)
{
    int idx = threadIdx.x; // DEP*H*N = 1024
    int d = idx/(Hq*Nq); int h = (idx/Nq)%Hq;
    double dt = exp((double)log_dt[d*Hq+h]);
    double Are = -exp((double)logAre[idx]);
    double Aim = (double)Aim_[idx];
    double dar = dt*Are, dai = dt*Aim;
    double er = exp(dar);
    double wr = er*cos(dai), wi = er*sin(dai);
    double em1r = wr - 1.0, em1i = wi;
    double den = Are*Are + Aim*Aim;
    double qr = (em1r*Are + em1i*Aim)/den;
    double qi = (em1i*Are - em1r*Aim)/den;
    double Cr = (double)Cre_[idx], Ci = (double)Cim_[idx];
    double eL = exp(dar*(double)LCq);
    double eG = exp(dar*(double)(LCq*GRPq));
    pw [idx*2+0]=(float)wr;  pw [idx*2+1]=(float)wi;
    pc2[idx*2+0]=(float)(2.0*(Cr*qr - Ci*qi)); pc2[idx*2+1]=(float)(2.0*(Cr*qi + Ci*qr));
    pwL[idx*2+0]=(float)(eL*cos(dai*(double)LCq));        pwL[idx*2+1]=(float)(eL*sin(dai*(double)LCq));
    pwG[idx*2+0]=(float)(eG*cos(dai*(double)(LCq*GRPq))); pwG[idx*2+1]=(float)(eG*sin(dai*(double)(LCq*GRPq)));
}

// ---------------- premix for depth 0 ----------------
__global__ void k_premix(const float* __restrict__ linW, const float* __restrict__ linB,
                         const float* __restrict__ eW, const float* __restrict__ eb,
                         float* __restrict__ ab0)
{
    int g = threadIdx.x;  // 32
    float a = 0.f, be = linB[g];
    #pragma unroll
    for (int h=0;h<Hq;h++){ a = fmaf(linW[g*Hq+h], eW[h], a); be = fmaf(linW[g*Hq+h], eb[h], be); }
    ab0[g] = a; ab0[32+g] = be;
}

// ---------------- k_first: u0 = relu(x*al+be), chunk-local scan_0 -> sloc ----------------
__global__ __launch_bounds__(256) void k_first(
    const float* __restrict__ x, const float* __restrict__ ab0,
    const float* __restrict__ pw, float* __restrict__ sloc)
{
    __shared__ float xs[LCq];
    int tid = threadIdx.x;
    int cg = blockIdx.x; int b = cg >> 10, c = cg & (NCq-1);
    if (tid < LCq) xs[tid] = x[(size_t)b*Lq + (size_t)c*LCq + tid];
    __syncthreads();
    int ch = tid >> 3, m = tid & 7;
    float wr = pw[(ch*Nq+m)*2], wi = pw[(ch*Nq+m)*2+1];
    float al = ab0[ch], be = ab0[32+ch];
    float sr = 0.f, si = 0.f;
    #pragma unroll 4
    for (int j=0;j<LCq;j++){
        float u = fmaf(xs[j], al, be); u = u>0.f?u:0.f;
        float nr = fmaf(wr, sr, fmaf(-wi, si, u));
        float ni = fmaf(wr, si, wi*sr);
        sr=nr; si=ni;
    }
    size_t sb = ((size_t)(b*NCq + c)*Hq + ch)*16;
    sloc[sb+m] = sr; sloc[sb+8+m] = si;
}

// ---------------- pass2: two-level prefix over chunks, block per (b,h) ----------------
__global__ __launch_bounds__(256) void k_pass2(const float* __restrict__ sloc,
    const float* __restrict__ pwL, const float* __restrict__ pwG, float* __restrict__ sini)
{
    __shared__ float aux[NGq*Nq*2];
    int bid = blockIdx.x; int b = bid >> 5, h = bid & 31;
    int tid = threadIdx.x;
    int n = tid & 7, g2 = tid >> 3;
    float wLr = pwL[(h*Nq+n)*2], wLi = pwL[(h*Nq+n)*2+1];
    float sr=0.f, si=0.f;
    for (int k=0;k<GRPq;k++){
        size_t off = ((size_t)(b*NCq + g2*GRPq+k)*Hq + h)*16;
        float lr = sloc[off+n], li = sloc[off+8+n];
        float nr = fmaf(wLr,sr, fmaf(-wLi,si, lr));
        float ni = fmaf(wLr,si, fmaf( wLi,sr, li));
        sr=nr; si=ni;
    }
    aux[(g2*8+n)*2+0]=sr; aux[(g2*8+n)*2+1]=si;
    __syncthreads();
    if (tid < 8) {
        float wGr = pwG[(h*Nq+tid)*2], wGi = pwG[(h*Nq+tid)*2+1];
        float pr=0.f, pi=0.f;
        for (int g=0; g<NGq; g++){
            float er_ = aux[(g*8+tid)*2+0], ei_ = aux[(g*8+tid)*2+1];
            aux[(g*8+tid)*2+0]=pr; aux[(g*8+tid)*2+1]=pi;
            float nr = fmaf(wGr,pr, fmaf(-wGi,pi, er_));
            float ni = fmaf(wGr,pi, fmaf( wGi,pr, ei_));
            pr=nr; pi=ni;
        }
    }
    __syncthreads();
    sr = aux[(g2*8+n)*2+0]; si = aux[(g2*8+n)*2+1];
    for (int k=0;k<GRPq;k++){
        size_t off = ((size_t)(b*NCq + g2*GRPq+k)*Hq + h)*16;
        float lr = sloc[off+n], li = sloc[off+8+n];
        sini[off+n] = sr; sini[off+8+n] = si;
        float nr = fmaf(wLr,sr, fmaf(-wLi,si, lr));
        float ni = fmaf(wLr,si, fmaf( wLi,sr, li));
        sr=nr; si=ni;
    }
}

// relu helper on float4
__device__ __forceinline__ float4 relu4(float4 v){
    v.x = v.x>0.f?v.x:0.f; v.y = v.y>0.f?v.y:0.f;
    v.z = v.z>0.f?v.z:0.f; v.w = v.w>0.f?v.w:0.f;
    return v;
}

// 32x32 mix for one tile row (row held in regs), weights via wave-uniform loads
__device__ __forceinline__ void mix_row_regs(const float hrow[Hq],
        const float* __restrict__ W, const float* __restrict__ Bv, float uo[Hq])
{
    #pragma unroll
    for (int g=0; g<Hq; g++){
        const float4* Wg = (const float4*)(W + g*Hq);
        float a0=0.f,a1=0.f,a2=0.f,a3=0.f;
        #pragma unroll
        for (int k=0;k<8;k++){
            float4 w = Wg[k];
            a0 = fmaf(w.x, hrow[4*k+0], a0);
            a1 = fmaf(w.y, hrow[4*k+1], a1);
            a2 = fmaf(w.z, hrow[4*k+2], a2);
            a3 = fmaf(w.w, hrow[4*k+3], a3);
        }
        float u = Bv[g] + ((a0+a1)+(a2+a3));
        uo[g] = u>0.f?u:0.f;
    }
}

// ---------------- fused per-depth kernel, MODE 0=first 1=mid 2=last ----------------
template<int MODE>
__global__ __launch_bounds__(256) void k_mainT(
    const float* __restrict__ x, float* __restrict__ hbuf,
    const float* __restrict__ eW, const float* __restrict__ eb,
    const float* __restrict__ ab0,
    const float* __restrict__ linW_d, const float* __restrict__ linB_d,
    const float* __restrict__ linW_n, const float* __restrict__ linB_n,
    const float* __restrict__ pw_d, const float* __restrict__ pc2_d,
    const float* __restrict__ pw_n,
    const float* __restrict__ sini, float* __restrict__ sloc,
    const float* __restrict__ Dskip, const float* __restrict__ film,
    const float* __restrict__ resw,
    const float* __restrict__ cW, const float* __restrict__ cb,
    float* __restrict__ out)
{
    __shared__ float4 tile4[CHB*LCq*8];   // 64 KB = 4096 float4
    float* tf = (float*)tile4;
    const int tid = threadIdx.x;
    const int cg0 = blockIdx.x * CHB;
    const int b = cg0 >> 10;
    const int c0 = cg0 & (NCq-1);
    const size_t base4 = (((size_t)b*Lq + (size_t)c0*LCq)*Hq) >> 2;
    const float4* hbr4 = (const float4*)hbuf + base4;
    float4*       hbw4 = (float4*)hbuf + base4;

    // ---- A: stage h_d into tile (swizzled) — 4096 float4 = 16 x 256
    if (MODE != 0) {
        for (int t=0;t<16;t++){
            int p = tid + t*256;
            float4 v = hbr4[p];
            int cc = p>>9, j=(p>>3)&63, k=p&7;
            tile4[(cc*LCq+j)*8 + (k ^ (j&7))] = v;
        }
        __syncthreads();
    }
    // ---- A1: mix_d -> tile rows in place (512 rows, 2/thread)
    {
        for (int t=0;t<2;t++){
            int r = tid + t*256;
            int cc = r>>6, j = r&63;
            int rb = (cc*LCq+j)*8;
            if (MODE == 0) {
                float xv = x[(size_t)b*Lq + (size_t)(c0+cc)*LCq + j];
                #pragma unroll
                for (int k=0;k<8;k++){
                    float4 a4 = ((const float4*)ab0)[k];
                    float4 b4 = ((const float4*)ab0)[8+k];
                    float4 u;
                    u.x = fmaf(xv,a4.x,b4.x); u.y = fmaf(xv,a4.y,b4.y);
                    u.z = fmaf(xv,a4.z,b4.z); u.w = fmaf(xv,a4.w,b4.w);
                    tile4[rb + (k ^ (j&7))] = relu4(u);
                }
            } else {
                float hrow[Hq], uo[Hq];
                #pragma unroll
                for (int k=0;k<8;k++) ((float4*)hrow)[k] = tile4[rb + (k^(j&7))];
                mix_row_regs(hrow, linW_d, linB_d, uo);
                #pragma unroll
                for (int k=0;k<8;k++)
                    tile4[rb + (k^(j&7))] = make_float4(uo[4*k],uo[4*k+1],uo[4*k+2],uo[4*k+3]);
            }
        }
    }
    __syncthreads();
    // ---- B: seeded scan_d + D-skip + FiLM + ReLU, in place on tile columns
    {
        int cc = tid>>5, ch = tid&31;
        int cg = c0 + cc;
        float wr[Nq],wi[Nq],cr[Nq],ci[Nq],sr[Nq],si[Nq];
        #pragma unroll
        for (int n=0;n<Nq;n++){
            wr[n]=pw_d[(ch*Nq+n)*2];  wi[n]=pw_d[(ch*Nq+n)*2+1];
            cr[n]=pc2_d[(ch*Nq+n)*2]; ci[n]=pc2_d[(ch*Nq+n)*2+1];
        }
        size_t sb = ((size_t)(b*NCq + cg)*Hq + ch)*16;
        #pragma unroll
        for (int n=0;n<Nq;n++){ sr[n]=sini[sb+n]; si[n]=sini[sb+8+n]; }
        float D = Dskip[ch];
        float gf = film[b*2*Hq + ch], bf = film[b*2*Hq + Hq + ch];
        int cbase = cc*LCq*32 + (ch&3);
        int chs = (ch>>2);
        #pragma unroll 2
        for (int j=0;j<LCq;j++){
            int fi = cbase + j*32 + ((chs ^ (j&7))<<2);
            float u = tf[fi];
            float y = D*u;
            #pragma unroll
            for (int n=0;n<Nq;n++){
                float nr = fmaf(wr[n],sr[n], fmaf(-wi[n],si[n], u));
                float ni = fmaf(wr[n],si[n], wi[n]*sr[n]);
                sr[n]=nr; si[n]=ni;
                y = fmaf(cr[n],nr,y);
                y = fmaf(-ci[n],ni,y);
            }
            y = fmaf(y,gf,bf);
            tf[fi] = y>0.f?y:0.f;
        }
    }
    __syncthreads();
    // ---- C: residual h_new = resw*h_d + y' -> tile (+hbuf for MODE!=2) — 16 x 256
    {
        for (int t=0;t<16;t++){
            int p = tid + t*256;
            int cc=p>>9, j=(p>>3)&63, k=p&7;
            int ti = (cc*LCq+j)*8 + (k^(j&7));
            float4 y4 = tile4[ti];
            float4 hg;
            if (MODE==0){
                float xv = x[(size_t)b*Lq + (size_t)(c0+cc)*LCq + j];
                float4 ew4 = ((const float4*)eW)[k], eb4 = ((const float4*)eb)[k];
                hg.x = fmaf(xv,ew4.x,eb4.x); hg.y = fmaf(xv,ew4.y,eb4.y);
                hg.z = fmaf(xv,ew4.z,eb4.z); hg.w = fmaf(xv,ew4.w,eb4.w);
            } else {
                hg = hbr4[p];
            }
            float4 rw4 = ((const float4*)resw)[k];
            float4 hn;
            hn.x = fmaf(rw4.x,hg.x,y4.x); hn.y = fmaf(rw4.y,hg.y,y4.y);
            hn.z = fmaf(rw4.z,hg.z,y4.z); hn.w = fmaf(rw4.w,hg.w,y4.w);
            if (MODE != 2) hbw4[p] = hn;
            tile4[ti] = hn;
        }
    }
    __syncthreads();
    if (MODE == 2) {
        for (int t=0;t<2;t++){
            int r = tid + t*256;
            int cc = r>>6, j = r&63;
            int rb = (cc*LCq+j)*8;
            float acc = 0.f;
            #pragma unroll
            for (int k=0;k<8;k++){
                float4 h4 = tile4[rb + (k^(j&7))];
                float4 w4 = ((const float4*)cW)[k];
                acc = fmaf(h4.x,w4.x,acc); acc = fmaf(h4.y,w4.y,acc);
                acc = fmaf(h4.z,w4.z,acc); acc = fmaf(h4.w,w4.w,acc);
            }
            size_t xo = (size_t)b*Lq + (size_t)(c0+cc)*LCq + j;
            out[xo] = x[xo]*tanhf(acc + cb[0]);
        }
        return;
    }
    // ---- C2: mix_{d+1} -> tile rows in place
    {
        for (int t=0;t<2;t++){
            int r = tid + t*256;
            int cc = r>>6, j = r&63;
            int rb = (cc*LCq+j)*8;
            float hrow[Hq], uo[Hq];
            #pragma unroll
            for (int k=0;k<8;k++) ((float4*)hrow)[k] = tile4[rb + (k^(j&7))];
            mix_row_regs(hrow, linW_n, linB_n, uo);
            #pragma unroll
            for (int k=0;k<8;k++)
                tile4[rb + (k^(j&7))] = make_float4(uo[4*k],uo[4*k+1],uo[4*k+2],uo[4*k+3]);
        }
    }
    __syncthreads();
    // ---- D: zero-seeded local scan_{d+1} -> sloc
    {
        int cc = tid>>5, ch = tid&31;
        int cg = c0 + cc;
        float vr[Nq],vi[Nq],tr_[Nq],ti_[Nq];
        #pragma unroll
        for (int n=0;n<Nq;n++){
            vr[n]=pw_n[(ch*Nq+n)*2]; vi[n]=pw_n[(ch*Nq+n)*2+1];
            tr_[n]=0.f; ti_[n]=0.f;
        }
        int cbase = cc*LCq*32 + (ch&3);
        int chs = (ch>>2);
        #pragma unroll 2
        for (int j=0;j<LCq;j++){
            int fi = cbase + j*32 + ((chs ^ (j&7))<<2);
            float u = tf[fi];
            #pragma unroll
            for (int n=0;n<Nq;n++){
                float nr = fmaf(vr[n],tr_[n], fmaf(-vi[n],ti_[n], u));
                float ni = fmaf(vr[n],ti_[n], vi[n]*tr_[n]);
                tr_[n]=nr; ti_[n]=ni;
            }
        }
        size_t sb = ((size_t)(b*NCq + cg)*Hq + ch)*16;
        #pragma unroll
        for (int n=0;n<Nq;n++){ sloc[sb+n]=tr_[n]; sloc[sb+8+n]=ti_[n]; }
    }
}

// ---------------- diagnostic flag ----------------
__global__ void k_flag(float* __restrict__ out, int code) { out[0] = (float)code; }

extern "C" void kernel_launch(void* const* d_in, const int* in_sizes, int n_in,
                              void* d_out, int out_size, void* d_ws, size_t ws_size,
                              hipStream_t stream)
{
    const float* x    = (const float*)d_in[0];
    const float* prm  = (const float*)d_in[1];
    const float* W1   = (const float*)d_in[2];  const float* b1 = (const float*)d_in[3];
    const float* W2   = (const float*)d_in[4];  const float* b2 = (const float*)d_in[5];
    const float* W3   = (const float*)d_in[6];  const float* b3 = (const float*)d_in[7];
    const float* eW   = (const float*)d_in[8];  const float* eb = (const float*)d_in[9];
    const float* linW = (const float*)d_in[10]; const float* linB = (const float*)d_in[11];
    const float* log_dt = (const float*)d_in[12]; const float* logAre = (const float*)d_in[13];
    const float* Aim  = (const float*)d_in[14]; const float* Cre = (const float*)d_in[15];
    const float* Cim  = (const float*)d_in[16]; const float* Dskip = (const float*)d_in[17];
    const float* filmW= (const float*)d_in[18]; const float* filmB = (const float*)d_in[19];
    const float* resw = (const float*)d_in[20]; const float* cW = (const float*)d_in[21];
    const float* cb   = (const float*)d_in[22];

    float* sloc = (float*)d_ws;                                    // 4194304 f
    float* sini = sloc + (size_t)Bq*NCq*Hq*16;                     // 4194304 f
    float* pw   = sini + (size_t)Bq*NCq*Hq*16;                     // 2048 f
    float* pc2  = pw  + DEPq*Hq*Nq*2;                              // 2048 f
    float* pwL  = pc2 + DEPq*Hq*Nq*2;                              // 2048 f
    float* pwG  = pwL + DEPq*Hq*Nq*2;                              // 2048 f
    float* film = pwG + DEPq*Hq*Nq*2;                              // 2048 f
    float* ab0  = film + DEPq*Bq*2*Hq;                             // 64 f
    float* hbuf = ab0 + 64;                                        // 16777216 f
    float* out  = (float*)d_out;
    size_t ws_needed = (char*)(hbuf + (size_t)Bq*Lq*Hq) - (char*)d_ws;

    hipLaunchKernelGGL(k_cond_film, dim3(DEPq), dim3(512), 0, stream,
                       prm,W1,b1,W2,b2,W3,b3,filmW,filmB,film);
    hipLaunchKernelGGL(k_s4params, dim3(1), dim3(DEPq*Hq*Nq), 0, stream,
                       log_dt,logAre,Aim,Cre,Cim,pw,pc2,pwL,pwG);
    hipLaunchKernelGGL(k_premix, dim3(1), dim3(Hq), 0, stream, linW, linB, eW, eb, ab0);
    hipLaunchKernelGGL(k_first, dim3(Bq*NCq), dim3(256), 0, stream, x, ab0, pw, sloc);

    const int main_grid = Bq*NCq/CHB;   // 1024
    for (int d=0; d<DEPq; d++){
        hipLaunchKernelGGL(k_pass2, dim3(Bq*Hq), dim3(256), 0, stream,
                           sloc, pwL + d*Hq*Nq*2, pwG + d*Hq*Nq*2, sini);
        int dn = (d < DEPq-1) ? d+1 : d;
        if (d == 0) {
            hipLaunchKernelGGL((k_mainT<0>), dim3(main_grid), dim3(256), 0, stream,
                x, hbuf, eW, eb, ab0,
                linW + d*Hq*Hq, linB + d*Hq, linW + dn*Hq*Hq, linB + dn*Hq,
                pw + d*Hq*Nq*2, pc2 + d*Hq*Nq*2, pw + dn*Hq*Nq*2,
                sini, sloc, Dskip + d*Hq, film + d*Bq*2*Hq, resw + d*Hq,
                cW, cb, out);
        } else if (d < DEPq-1) {
            hipLaunchKernelGGL((k_mainT<1>), dim3(main_grid), dim3(256), 0, stream,
                x, hbuf, eW, eb, ab0,
                linW + d*Hq*Hq, linB + d*Hq, linW + dn*Hq*Hq, linB + dn*Hq,
                pw + d*Hq*Nq*2, pc2 + d*Hq*Nq*2, pw + dn*Hq*Nq*2,
                sini, sloc, Dskip + d*Hq, film + d*Bq*2*Hq, resw + d*Hq,
                cW, cb, out);
        } else {
            hipLaunchKernelGGL((k_mainT<2>), dim3(main_grid), dim3(256), 0, stream,
                x, hbuf, eW, eb, ab0,
                linW + d*Hq*Hq, linB + d*Hq, linW + dn*Hq*Hq, linB + dn*Hq,
                pw + d*Hq*Nq*2, pc2 + d*Hq*Nq*2, pw + dn*Hq*Nq*2,
                sini, sloc, Dskip + d*Hq, film + d*Bq*2*Hq, resw + d*Hq,
                cW, cb, out);
        }
    }

    static const int expected[23] = {
        Bq*Lq, Bq*2, 32, 16, 512, 32, 1024, 32, Hq, Hq,
        DEPq*Hq*Hq, DEPq*Hq, DEPq*Hq, DEPq*Hq*Nq, DEPq*Hq*Nq, DEPq*Hq*Nq, DEPq*Hq*Nq,
        DEPq*Hq, DEPq*2*Hq*32, DEPq*2*Hq, DEPq*Hq, Hq, 1
    };
    int code = 0;
    if (n_in != 23) code = 99;
    else { for (int i = 0; i < 23; i++) if (in_sizes[i] != expected[i]) { code = 100 + i; break; } }
    if (!code && ws_size < ws_needed) code = 200;
    if (code) hipLaunchKernelGGL(k_flag, dim3(1), dim3(1), 0, stream, out, code);
}

// Round 13
// 849.606 us; speedup vs baseline: 1.9562x; 1.1004x over previous
//
#include <hip/hip_runtime.h>
#include <math.h>

#define Bq 8
#define Lq 65536
#define Hq 32
#define Nq 8
#define DEPq 4
#define LCq 64
#define NCq (Lq/LCq)     // 1024 chunks per b
#define GRPq 32
#define NGq  (NCq/GRPq)  // 32 groups
#define CHB 4            // chunks per k_main block (32KB tile)
#define TPB 128          // threads per k_main block

// ---------------- conditioning MLP + FiLM ----------------
__global__ void k_cond_film(const float* __restrict__ prm,
                            const float* __restrict__ W1, const float* __restrict__ b1,
                            const float* __restrict__ W2, const float* __restrict__ b2,
                            const float* __restrict__ W3, const float* __restrict__ b3,
                            const float* __restrict__ filmW, const float* __restrict__ filmB,
                            float* __restrict__ film /* [DEP][B][2H] */)
{
    __shared__ float cond[Bq][32];
    int tid = threadIdx.x, d = blockIdx.x;
    if (tid < Bq) {
        float p0 = prm[tid*2+0], p1 = prm[tid*2+1];
        float c1[16];
        #pragma unroll
        for (int i=0;i<16;i++){ float v = W1[i*2+0]*p0 + W1[i*2+1]*p1 + b1[i]; c1[i]=v>0.f?v:0.f; }
        float c2[32];
        #pragma unroll
        for (int i=0;i<32;i++){ float a=b2[i];
            #pragma unroll
            for(int j=0;j<16;j++) a = fmaf(W2[i*16+j], c1[j], a);
            c2[i]=a>0.f?a:0.f; }
        #pragma unroll
        for (int i=0;i<32;i++){ float a=b3[i];
            #pragma unroll
            for(int j=0;j<32;j++) a = fmaf(W3[i*32+j], c2[j], a);
            cond[tid][i]=a>0.f?a:0.f; }
    }
    __syncthreads();
    int b = tid>>6, k = tid&63;
    float a = filmB[d*2*Hq + k];
    #pragma unroll
    for (int j=0;j<32;j++) a = fmaf(cond[b][j], filmW[(d*2*Hq + k)*32 + j], a);
    film[(d*Bq + b)*2*Hq + k] = a;
}

// ---------------- S4D derived params ----------------
__global__ void k_s4params(const float* __restrict__ log_dt, const float* __restrict__ logAre,
                           const float* __restrict__ Aim_, const float* __restrict__ Cre_,
                           const float* __restrict__ Cim_,
                           float* __restrict__ pw, float* __restrict__ pc2,
                           float* __restrict__ pwL, float* __restrict__ pwG)
{
    int idx = threadIdx.x; // DEP*H*N = 1024
    int d = idx/(Hq*Nq); int h = (idx/Nq)%Hq;
    double dt = exp((double)log_dt[d*Hq+h]);
    double Are = -exp((double)logAre[idx]);
    double Aim = (double)Aim_[idx];
    double dar = dt*Are, dai = dt*Aim;
    double er = exp(dar);
    double wr = er*cos(dai), wi = er*sin(dai);
    double em1r = wr - 1.0, em1i = wi;
    double den = Are*Are + Aim*Aim;
    double qr = (em1r*Are + em1i*Aim)/den;
    double qi = (em1i*Are - em1r*Aim)/den;
    double Cr = (double)Cre_[idx], Ci = (double)Cim_[idx];
    double eL = exp(dar*(double)LCq);
    double eG = exp(dar*(double)(LCq*GRPq));
    pw [idx*2+0]=(float)wr;  pw [idx*2+1]=(float)wi;
    pc2[idx*2+0]=(float)(2.0*(Cr*qr - Ci*qi)); pc2[idx*2+1]=(float)(2.0*(Cr*qi + Ci*qr));
    pwL[idx*2+0]=(float)(eL*cos(dai*(double)LCq));        pwL[idx*2+1]=(float)(eL*sin(dai*(double)LCq));
    pwG[idx*2+0]=(float)(eG*cos(dai*(double)(LCq*GRPq))); pwG[idx*2+1]=(float)(eG*sin(dai*(double)(LCq*GRPq)));
}

// ---------------- premix for depth 0 ----------------
__global__ void k_premix(const float* __restrict__ linW, const float* __restrict__ linB,
                         const float* __restrict__ eW, const float* __restrict__ eb,
                         float* __restrict__ ab0)
{
    int g = threadIdx.x;  // 32
    float a = 0.f, be = linB[g];
    #pragma unroll
    for (int h=0;h<Hq;h++){ a = fmaf(linW[g*Hq+h], eW[h], a); be = fmaf(linW[g*Hq+h], eb[h], be); }
    ab0[g] = a; ab0[32+g] = be;
}

// ---------------- k_first: u0 = relu(x*al+be), chunk-local scan_0 -> sloc ----------------
__global__ __launch_bounds__(256) void k_first(
    const float* __restrict__ x, const float* __restrict__ ab0,
    const float* __restrict__ pw, float* __restrict__ sloc)
{
    __shared__ float xs[LCq];
    int tid = threadIdx.x;
    int cg = blockIdx.x; int b = cg >> 10, c = cg & (NCq-1);
    if (tid < LCq) xs[tid] = x[(size_t)b*Lq + (size_t)c*LCq + tid];
    __syncthreads();
    int ch = tid >> 3, m = tid & 7;
    float wr = pw[(ch*Nq+m)*2], wi = pw[(ch*Nq+m)*2+1];
    float al = ab0[ch], be = ab0[32+ch];
    float sr = 0.f, si = 0.f;
    #pragma unroll 4
    for (int j=0;j<LCq;j++){
        float u = fmaf(xs[j], al, be); u = u>0.f?u:0.f;
        float nr = fmaf(wr, sr, fmaf(-wi, si, u));
        float ni = fmaf(wr, si, wi*sr);
        sr=nr; si=ni;
    }
    size_t sb = ((size_t)(b*NCq + c)*Hq + ch)*16;
    sloc[sb+m] = sr; sloc[sb+8+m] = si;
}

// ---------------- pass2: two-level prefix over chunks, block per (b,h) ----------------
__global__ __launch_bounds__(256) void k_pass2(const float* __restrict__ sloc,
    const float* __restrict__ pwL, const float* __restrict__ pwG, float* __restrict__ sini)
{
    __shared__ float aux[NGq*Nq*2];
    int bid = blockIdx.x; int b = bid >> 5, h = bid & 31;
    int tid = threadIdx.x;
    int n = tid & 7, g2 = tid >> 3;
    float wLr = pwL[(h*Nq+n)*2], wLi = pwL[(h*Nq+n)*2+1];
    float sr=0.f, si=0.f;
    for (int k=0;k<GRPq;k++){
        size_t off = ((size_t)(b*NCq + g2*GRPq+k)*Hq + h)*16;
        float lr = sloc[off+n], li = sloc[off+8+n];
        float nr = fmaf(wLr,sr, fmaf(-wLi,si, lr));
        float ni = fmaf(wLr,si, fmaf( wLi,sr, li));
        sr=nr; si=ni;
    }
    aux[(g2*8+n)*2+0]=sr; aux[(g2*8+n)*2+1]=si;
    __syncthreads();
    if (tid < 8) {
        float wGr = pwG[(h*Nq+tid)*2], wGi = pwG[(h*Nq+tid)*2+1];
        float pr=0.f, pi=0.f;
        for (int g=0; g<NGq; g++){
            float er_ = aux[(g*8+tid)*2+0], ei_ = aux[(g*8+tid)*2+1];
            aux[(g*8+tid)*2+0]=pr; aux[(g*8+tid)*2+1]=pi;
            float nr = fmaf(wGr,pr, fmaf(-wGi,pi, er_));
            float ni = fmaf(wGr,pi, fmaf( wGi,pr, ei_));
            pr=nr; pi=ni;
        }
    }
    __syncthreads();
    sr = aux[(g2*8+n)*2+0]; si = aux[(g2*8+n)*2+1];
    for (int k=0;k<GRPq;k++){
        size_t off = ((size_t)(b*NCq + g2*GRPq+k)*Hq + h)*16;
        float lr = sloc[off+n], li = sloc[off+8+n];
        sini[off+n] = sr; sini[off+8+n] = si;
        float nr = fmaf(wLr,sr, fmaf(-wLi,si, lr));
        float ni = fmaf(wLr,si, fmaf( wLi,sr, li));
        sr=nr; si=ni;
    }
}

// relu helper on float4
__device__ __forceinline__ float4 relu4(float4 v){
    v.x = v.x>0.f?v.x:0.f; v.y = v.y>0.f?v.y:0.f;
    v.z = v.z>0.f?v.z:0.f; v.w = v.w>0.f?v.w:0.f;
    return v;
}

// 32x32 mix for one tile row (row held in regs), weights via wave-uniform loads
__device__ __forceinline__ void mix_row_regs(const float hrow[Hq],
        const float* __restrict__ W, const float* __restrict__ Bv, float uo[Hq])
{
    #pragma unroll
    for (int g=0; g<Hq; g++){
        const float4* Wg = (const float4*)(W + g*Hq);
        float a0=0.f,a1=0.f,a2=0.f,a3=0.f;
        #pragma unroll
        for (int k=0;k<8;k++){
            float4 w = Wg[k];
            a0 = fmaf(w.x, hrow[4*k+0], a0);
            a1 = fmaf(w.y, hrow[4*k+1], a1);
            a2 = fmaf(w.z, hrow[4*k+2], a2);
            a3 = fmaf(w.w, hrow[4*k+3], a3);
        }
        float u = Bv[g] + ((a0+a1)+(a2+a3));
        uo[g] = u>0.f?u:0.f;
    }
}

// ---------------- fused per-depth kernel, MODE 0=first 1=mid 2=last ----------------
// 128 threads, CHB=4 chunks, 32KB tile -> ~5 blocks/CU resident
template<int MODE>
__global__ __launch_bounds__(TPB, 4) void k_mainT(
    const float* __restrict__ x, float* __restrict__ hbuf,
    const float* __restrict__ eW, const float* __restrict__ eb,
    const float* __restrict__ ab0,
    const float* __restrict__ linW_d, const float* __restrict__ linB_d,
    const float* __restrict__ linW_n, const float* __restrict__ linB_n,
    const float* __restrict__ pw_d, const float* __restrict__ pc2_d,
    const float* __restrict__ pw_n,
    const float* __restrict__ sini, float* __restrict__ sloc,
    const float* __restrict__ Dskip, const float* __restrict__ film,
    const float* __restrict__ resw,
    const float* __restrict__ cW, const float* __restrict__ cb,
    float* __restrict__ out)
{
    __shared__ float4 tile4[CHB*LCq*8];   // 32 KB = 2048 float4
    float* tf = (float*)tile4;
    const int tid = threadIdx.x;
    const int cg0 = blockIdx.x * CHB;
    const int b = cg0 >> 10;
    const int c0 = cg0 & (NCq-1);
    const size_t base4 = (((size_t)b*Lq + (size_t)c0*LCq)*Hq) >> 2;
    const float4* hbr4 = (const float4*)hbuf + base4;
    float4*       hbw4 = (float4*)hbuf + base4;

    // ---- A: stage h_d into tile (swizzled) — 2048 float4 = 16 x 128
    if (MODE != 0) {
        for (int t=0;t<16;t++){
            int p = tid + t*TPB;
            float4 v = hbr4[p];
            int cc = p>>9, j=(p>>3)&63, k=p&7;
            tile4[(cc*LCq+j)*8 + (k ^ (j&7))] = v;
        }
        __syncthreads();
    }
    // ---- A1: mix_d -> tile rows in place (256 rows, 2/thread)
    {
        for (int t=0;t<2;t++){
            int r = tid + t*TPB;
            int cc = r>>6, j = r&63;
            int rb = (cc*LCq+j)*8;
            if (MODE == 0) {
                float xv = x[(size_t)b*Lq + (size_t)(c0+cc)*LCq + j];
                #pragma unroll
                for (int k=0;k<8;k++){
                    float4 a4 = ((const float4*)ab0)[k];
                    float4 b4 = ((const float4*)ab0)[8+k];
                    float4 u;
                    u.x = fmaf(xv,a4.x,b4.x); u.y = fmaf(xv,a4.y,b4.y);
                    u.z = fmaf(xv,a4.z,b4.z); u.w = fmaf(xv,a4.w,b4.w);
                    tile4[rb + (k ^ (j&7))] = relu4(u);
                }
            } else {
                float hrow[Hq], uo[Hq];
                #pragma unroll
                for (int k=0;k<8;k++) ((float4*)hrow)[k] = tile4[rb + (k^(j&7))];
                mix_row_regs(hrow, linW_d, linB_d, uo);
                #pragma unroll
                for (int k=0;k<8;k++)
                    tile4[rb + (k^(j&7))] = make_float4(uo[4*k],uo[4*k+1],uo[4*k+2],uo[4*k+3]);
            }
        }
    }
    __syncthreads();
    // ---- B: seeded scan_d + D-skip + FiLM + ReLU, in place on tile columns
    {
        int cc = tid>>5, ch = tid&31;
        int cg = c0 + cc;
        float wr[Nq],wi[Nq],cr[Nq],ci[Nq],sr[Nq],si[Nq];
        #pragma unroll
        for (int n=0;n<Nq;n++){
            wr[n]=pw_d[(ch*Nq+n)*2];  wi[n]=pw_d[(ch*Nq+n)*2+1];
            cr[n]=pc2_d[(ch*Nq+n)*2]; ci[n]=pc2_d[(ch*Nq+n)*2+1];
        }
        size_t sb = ((size_t)(b*NCq + cg)*Hq + ch)*16;
        #pragma unroll
        for (int n=0;n<Nq;n++){ sr[n]=sini[sb+n]; si[n]=sini[sb+8+n]; }
        float D = Dskip[ch];
        float gf = film[b*2*Hq + ch], bf = film[b*2*Hq + Hq + ch];
        int cbase = cc*LCq*32 + (ch&3);
        int chs = (ch>>2);
        #pragma unroll 2
        for (int j=0;j<LCq;j++){
            int fi = cbase + j*32 + ((chs ^ (j&7))<<2);
            float u = tf[fi];
            float y = D*u;
            #pragma unroll
            for (int n=0;n<Nq;n++){
                float nr = fmaf(wr[n],sr[n], fmaf(-wi[n],si[n], u));
                float ni = fmaf(wr[n],si[n], wi[n]*sr[n]);
                sr[n]=nr; si[n]=ni;
                y = fmaf(cr[n],nr,y);
                y = fmaf(-ci[n],ni,y);
            }
            y = fmaf(y,gf,bf);
            tf[fi] = y>0.f?y:0.f;
        }
    }
    __syncthreads();
    // ---- C: residual h_new = resw*h_d + y' -> tile (+hbuf for MODE!=2) — 16 x 128
    {
        for (int t=0;t<16;t++){
            int p = tid + t*TPB;
            int cc=p>>9, j=(p>>3)&63, k=p&7;
            int ti = (cc*LCq+j)*8 + (k^(j&7));
            float4 y4 = tile4[ti];
            float4 hg;
            if (MODE==0){
                float xv = x[(size_t)b*Lq + (size_t)(c0+cc)*LCq + j];
                float4 ew4 = ((const float4*)eW)[k], eb4 = ((const float4*)eb)[k];
                hg.x = fmaf(xv,ew4.x,eb4.x); hg.y = fmaf(xv,ew4.y,eb4.y);
                hg.z = fmaf(xv,ew4.z,eb4.z); hg.w = fmaf(xv,ew4.w,eb4.w);
            } else {
                hg = hbr4[p];
            }
            float4 rw4 = ((const float4*)resw)[k];
            float4 hn;
            hn.x = fmaf(rw4.x,hg.x,y4.x); hn.y = fmaf(rw4.y,hg.y,y4.y);
            hn.z = fmaf(rw4.z,hg.z,y4.z); hn.w = fmaf(rw4.w,hg.w,y4.w);
            if (MODE != 2) hbw4[p] = hn;
            tile4[ti] = hn;
        }
    }
    __syncthreads();
    if (MODE == 2) {
        for (int t=0;t<2;t++){
            int r = tid + t*TPB;
            int cc = r>>6, j = r&63;
            int rb = (cc*LCq+j)*8;
            float acc = 0.f;
            #pragma unroll
            for (int k=0;k<8;k++){
                float4 h4 = tile4[rb + (k^(j&7))];
                float4 w4 = ((const float4*)cW)[k];
                acc = fmaf(h4.x,w4.x,acc); acc = fmaf(h4.y,w4.y,acc);
                acc = fmaf(h4.z,w4.z,acc); acc = fmaf(h4.w,w4.w,acc);
            }
            size_t xo = (size_t)b*Lq + (size_t)(c0+cc)*LCq + j;
            out[xo] = x[xo]*tanhf(acc + cb[0]);
        }
        return;
    }
    // ---- C2: mix_{d+1} -> tile rows in place
    {
        for (int t=0;t<2;t++){
            int r = tid + t*TPB;
            int cc = r>>6, j = r&63;
            int rb = (cc*LCq+j)*8;
            float hrow[Hq], uo[Hq];
            #pragma unroll
            for (int k=0;k<8;k++) ((float4*)hrow)[k] = tile4[rb + (k^(j&7))];
            mix_row_regs(hrow, linW_n, linB_n, uo);
            #pragma unroll
            for (int k=0;k<8;k++)
                tile4[rb + (k^(j&7))] = make_float4(uo[4*k],uo[4*k+1],uo[4*k+2],uo[4*k+3]);
        }
    }
    __syncthreads();
    // ---- D: zero-seeded local scan_{d+1} -> sloc
    {
        int cc = tid>>5, ch = tid&31;
        int cg = c0 + cc;
        float vr[Nq],vi[Nq],tr_[Nq],ti_[Nq];
        #pragma unroll
        for (int n=0;n<Nq;n++){
            vr[n]=pw_n[(ch*Nq+n)*2]; vi[n]=pw_n[(ch*Nq+n)*2+1];
            tr_[n]=0.f; ti_[n]=0.f;
        }
        int cbase = cc*LCq*32 + (ch&3);
        int chs = (ch>>2);
        #pragma unroll 2
        for (int j=0;j<LCq;j++){
            int fi = cbase + j*32 + ((chs ^ (j&7))<<2);
            float u = tf[fi];
            #pragma unroll
            for (int n=0;n<Nq;n++){
                float nr = fmaf(vr[n],tr_[n], fmaf(-vi[n],ti_[n], u));
                float ni = fmaf(vr[n],ti_[n], vi[n]*tr_[n]);
                tr_[n]=nr; ti_[n]=ni;
            }
        }
        size_t sb = ((size_t)(b*NCq + cg)*Hq + ch)*16;
        #pragma unroll
        for (int n=0;n<Nq;n++){ sloc[sb+n]=tr_[n]; sloc[sb+8+n]=ti_[n]; }
    }
}

// ---------------- diagnostic flag ----------------
__global__ void k_flag(float* __restrict__ out, int code) { out[0] = (float)code; }

extern "C" void kernel_launch(void* const* d_in, const int* in_sizes, int n_in,
                              void* d_out, int out_size, void* d_ws, size_t ws_size,
                              hipStream_t stream)
{
    const float* x    = (const float*)d_in[0];
    const float* prm  = (const float*)d_in[1];
    const float* W1   = (const float*)d_in[2];  const float* b1 = (const float*)d_in[3];
    const float* W2   = (const float*)d_in[4];  const float* b2 = (const float*)d_in[5];
    const float* W3   = (const float*)d_in[6];  const float* b3 = (const float*)d_in[7];
    const float* eW   = (const float*)d_in[8];  const float* eb = (const float*)d_in[9];
    const float* linW = (const float*)d_in[10]; const float* linB = (const float*)d_in[11];
    const float* log_dt = (const float*)d_in[12]; const float* logAre = (const float*)d_in[13];
    const float* Aim  = (const float*)d_in[14]; const float* Cre = (const float*)d_in[15];
    const float* Cim  = (const float*)d_in[16]; const float* Dskip = (const float*)d_in[17];
    const float* filmW= (const float*)d_in[18]; const float* filmB = (const float*)d_in[19];
    const float* resw = (const float*)d_in[20]; const float* cW = (const float*)d_in[21];
    const float* cb   = (const float*)d_in[22];

    float* sloc = (float*)d_ws;                                    // 4194304 f
    float* sini = sloc + (size_t)Bq*NCq*Hq*16;                     // 4194304 f
    float* pw   = sini + (size_t)Bq*NCq*Hq*16;                     // 2048 f
    float* pc2  = pw  + DEPq*Hq*Nq*2;                              // 2048 f
    float* pwL  = pc2 + DEPq*Hq*Nq*2;                              // 2048 f
    float* pwG  = pwL + DEPq*Hq*Nq*2;                              // 2048 f
    float* film = pwG + DEPq*Hq*Nq*2;                              // 2048 f
    float* ab0  = film + DEPq*Bq*2*Hq;                             // 64 f
    float* hbuf = ab0 + 64;                                        // 16777216 f
    float* out  = (float*)d_out;
    size_t ws_needed = (char*)(hbuf + (size_t)Bq*Lq*Hq) - (char*)d_ws;

    hipLaunchKernelGGL(k_cond_film, dim3(DEPq), dim3(512), 0, stream,
                       prm,W1,b1,W2,b2,W3,b3,filmW,filmB,film);
    hipLaunchKernelGGL(k_s4params, dim3(1), dim3(DEPq*Hq*Nq), 0, stream,
                       log_dt,logAre,Aim,Cre,Cim,pw,pc2,pwL,pwG);
    hipLaunchKernelGGL(k_premix, dim3(1), dim3(Hq), 0, stream, linW, linB, eW, eb, ab0);
    hipLaunchKernelGGL(k_first, dim3(Bq*NCq), dim3(256), 0, stream, x, ab0, pw, sloc);

    const int main_grid = Bq*NCq/CHB;   // 2048
    for (int d=0; d<DEPq; d++){
        hipLaunchKernelGGL(k_pass2, dim3(Bq*Hq), dim3(256), 0, stream,
                           sloc, pwL + d*Hq*Nq*2, pwG + d*Hq*Nq*2, sini);
        int dn = (d < DEPq-1) ? d+1 : d;
        if (d == 0) {
            hipLaunchKernelGGL((k_mainT<0>), dim3(main_grid), dim3(TPB), 0, stream,
                x, hbuf, eW, eb, ab0,
                linW + d*Hq*Hq, linB + d*Hq, linW + dn*Hq*Hq, linB + dn*Hq,
                pw + d*Hq*Nq*2, pc2 + d*Hq*Nq*2, pw + dn*Hq*Nq*2,
                sini, sloc, Dskip + d*Hq, film + d*Bq*2*Hq, resw + d*Hq,
                cW, cb, out);
        } else if (d < DEPq-1) {
            hipLaunchKernelGGL((k_mainT<1>), dim3(main_grid), dim3(TPB), 0, stream,
                x, hbuf, eW, eb, ab0,
                linW + d*Hq*Hq, linB + d*Hq, linW + dn*Hq*Hq, linB + dn*Hq,
                pw + d*Hq*Nq*2, pc2 + d*Hq*Nq*2, pw + dn*Hq*Nq*2,
                sini, sloc, Dskip + d*Hq, film + d*Bq*2*Hq, resw + d*Hq,
                cW, cb, out);
        } else {
            hipLaunchKernelGGL((k_mainT<2>), dim3(main_grid), dim3(TPB), 0, stream,
                x, hbuf, eW, eb, ab0,
                linW + d*Hq*Hq, linB + d*Hq, linW + dn*Hq*Hq, linB + dn*Hq,
                pw + d*Hq*Nq*2, pc2 + d*Hq*Nq*2, pw + dn*Hq*Nq*2,
                sini, sloc, Dskip + d*Hq, film + d*Bq*2*Hq, resw + d*Hq,
                cW, cb, out);
        }
    }

    static const int expected[23] = {
        Bq*Lq, Bq*2, 32, 16, 512, 32, 1024, 32, Hq, Hq,
        DEPq*Hq*Hq, DEPq*Hq, DEPq*Hq, DEPq*Hq*Nq, DEPq*Hq*Nq, DEPq*Hq*Nq, DEPq*Hq*Nq,
        DEPq*Hq, DEPq*2*Hq*32, DEPq*2*Hq, DEPq*Hq, Hq, 1
    };
    int code = 0;
    if (n_in != 23) code = 99;
    else { for (int i = 0; i < 23; i++) if (in_sizes[i] != expected[i]) { code = 100 + i; break; } }
    if (!code && ws_size < ws_needed) code = 200;
    if (code) hipLaunchKernelGGL(k_flag, dim3(1), dim3(1), 0, stream, out, code);
}

// Round 14
// 579.735 us; speedup vs baseline: 2.8669x; 1.4655x over previous
//
#include <hip/hip_runtime.h>
#include <math.h>

#define Bq 8
#define Lq 65536
#define Hq 32
#define Nq 8
#define DEPq 4
#define LCq 64
#define NCq (Lq/LCq)     // 1024 chunks per b
#define GRPq 32
#define NGq  (NCq/GRPq)  // 32 groups
#define CHB 4            // chunks per k_main block
#define TPB (CHB*Hq)     // 128 threads

// ---------------- conditioning MLP + FiLM ----------------
__global__ void k_cond_film(const float* __restrict__ prm,
                            const float* __restrict__ W1, const float* __restrict__ b1,
                            const float* __restrict__ W2, const float* __restrict__ b2,
                            const float* __restrict__ W3, const float* __restrict__ b3,
                            const float* __restrict__ filmW, const float* __restrict__ filmB,
                            float* __restrict__ film /* [DEP][B][2H] */)
{
    __shared__ float cond[Bq][32];
    int tid = threadIdx.x, d = blockIdx.x;
    if (tid < Bq) {
        float p0 = prm[tid*2+0], p1 = prm[tid*2+1];
        float c1[16];
        #pragma unroll
        for (int i=0;i<16;i++){ float v = W1[i*2+0]*p0 + W1[i*2+1]*p1 + b1[i]; c1[i]=v>0.f?v:0.f; }
        float c2[32];
        #pragma unroll
        for (int i=0;i<32;i++){ float a=b2[i];
            #pragma unroll
            for(int j=0;j<16;j++) a = fmaf(W2[i*16+j], c1[j], a);
            c2[i]=a>0.f?a:0.f; }
        #pragma unroll
        for (int i=0;i<32;i++){ float a=b3[i];
            #pragma unroll
            for(int j=0;j<32;j++) a = fmaf(W3[i*32+j], c2[j], a);
            cond[tid][i]=a>0.f?a:0.f; }
    }
    __syncthreads();
    int b = tid>>6, k = tid&63;
    float a = filmB[d*2*Hq + k];
    #pragma unroll
    for (int j=0;j<32;j++) a = fmaf(cond[b][j], filmW[(d*2*Hq + k)*32 + j], a);
    film[(d*Bq + b)*2*Hq + k] = a;
}

// ---------------- S4D derived params ----------------
__global__ void k_s4params(const float* __restrict__ log_dt, const float* __restrict__ logAre,
                           const float* __restrict__ Aim_, const float* __restrict__ Cre_,
                           const float* __restrict__ Cim_,
                           float* __restrict__ pw, float* __restrict__ pc2,
                           float* __restrict__ pwL, float* __restrict__ pwG)
{
    int idx = threadIdx.x; // DEP*H*N = 1024
    int d = idx/(Hq*Nq); int h = (idx/Nq)%Hq;
    double dt = exp((double)log_dt[d*Hq+h]);
    double Are = -exp((double)logAre[idx]);
    double Aim = (double)Aim_[idx];
    double dar = dt*Are, dai = dt*Aim;
    double er = exp(dar);
    double wr = er*cos(dai), wi = er*sin(dai);
    double em1r = wr - 1.0, em1i = wi;
    double den = Are*Are + Aim*Aim;
    double qr = (em1r*Are + em1i*Aim)/den;
    double qi = (em1i*Are - em1r*Aim)/den;
    double Cr = (double)Cre_[idx], Ci = (double)Cim_[idx];
    double eL = exp(dar*(double)LCq);
    double eG = exp(dar*(double)(LCq*GRPq));
    pw [idx*2+0]=(float)wr;  pw [idx*2+1]=(float)wi;
    pc2[idx*2+0]=(float)(2.0*(Cr*qr - Ci*qi)); pc2[idx*2+1]=(float)(2.0*(Cr*qi + Ci*qr));
    pwL[idx*2+0]=(float)(eL*cos(dai*(double)LCq));        pwL[idx*2+1]=(float)(eL*sin(dai*(double)LCq));
    pwG[idx*2+0]=(float)(eG*cos(dai*(double)(LCq*GRPq))); pwG[idx*2+1]=(float)(eG*sin(dai*(double)(LCq*GRPq)));
}

// ---------------- premix for depth 0 ----------------
__global__ void k_premix(const float* __restrict__ linW, const float* __restrict__ linB,
                         const float* __restrict__ eW, const float* __restrict__ eb,
                         float* __restrict__ ab0)
{
    int g = threadIdx.x;  // 32
    float a = 0.f, be = linB[g];
    #pragma unroll
    for (int h=0;h<Hq;h++){ a = fmaf(linW[g*Hq+h], eW[h], a); be = fmaf(linW[g*Hq+h], eb[h], be); }
    ab0[g] = a; ab0[32+g] = be;
}

// ---------------- k_first: u0 = relu(x*al+be), chunk-local scan_0 -> sloc ----------------
__global__ __launch_bounds__(256) void k_first(
    const float* __restrict__ x, const float* __restrict__ ab0,
    const float* __restrict__ pw, float* __restrict__ sloc)
{
    __shared__ float xs[LCq];
    int tid = threadIdx.x;
    int cg = blockIdx.x; int b = cg >> 10, c = cg & (NCq-1);
    if (tid < LCq) xs[tid] = x[(size_t)b*Lq + (size_t)c*LCq + tid];
    __syncthreads();
    int ch = tid >> 3, m = tid & 7;
    float wr = pw[(ch*Nq+m)*2], wi = pw[(ch*Nq+m)*2+1];
    float al = ab0[ch], be = ab0[32+ch];
    float sr = 0.f, si = 0.f;
    #pragma unroll 4
    for (int j=0;j<LCq;j++){
        float u = fmaf(xs[j], al, be); u = u>0.f?u:0.f;
        float nr = fmaf(wr, sr, fmaf(-wi, si, u));
        float ni = fmaf(wr, si, wi*sr);
        sr=nr; si=ni;
    }
    size_t sb = ((size_t)(b*NCq + c)*Hq + ch)*16;
    sloc[sb+m] = sr; sloc[sb+8+m] = si;
}

// ---------------- pass2: two-level prefix over chunks, block per (b,h) ----------------
__global__ __launch_bounds__(256) void k_pass2(const float* __restrict__ sloc,
    const float* __restrict__ pwL, const float* __restrict__ pwG, float* __restrict__ sini)
{
    __shared__ float aux[NGq*Nq*2];
    int bid = blockIdx.x; int b = bid >> 5, h = bid & 31;
    int tid = threadIdx.x;
    int n = tid & 7, g2 = tid >> 3;
    float wLr = pwL[(h*Nq+n)*2], wLi = pwL[(h*Nq+n)*2+1];
    float sr=0.f, si=0.f;
    for (int k=0;k<GRPq;k++){
        size_t off = ((size_t)(b*NCq + g2*GRPq+k)*Hq + h)*16;
        float lr = sloc[off+n], li = sloc[off+8+n];
        float nr = fmaf(wLr,sr, fmaf(-wLi,si, lr));
        float ni = fmaf(wLr,si, fmaf( wLi,sr, li));
        sr=nr; si=ni;
    }
    aux[(g2*8+n)*2+0]=sr; aux[(g2*8+n)*2+1]=si;
    __syncthreads();
    if (tid < 8) {
        float wGr = pwG[(h*Nq+tid)*2], wGi = pwG[(h*Nq+tid)*2+1];
        float pr=0.f, pi=0.f;
        for (int g=0; g<NGq; g++){
            float er_ = aux[(g*8+tid)*2+0], ei_ = aux[(g*8+tid)*2+1];
            aux[(g*8+tid)*2+0]=pr; aux[(g*8+tid)*2+1]=pi;
            float nr = fmaf(wGr,pr, fmaf(-wGi,pi, er_));
            float ni = fmaf(wGr,pi, fmaf( wGi,pr, ei_));
            pr=nr; pi=ni;
        }
    }
    __syncthreads();
    sr = aux[(g2*8+n)*2+0]; si = aux[(g2*8+n)*2+1];
    for (int k=0;k<GRPq;k++){
        size_t off = ((size_t)(b*NCq + g2*GRPq+k)*Hq + h)*16;
        float lr = sloc[off+n], li = sloc[off+8+n];
        sini[off+n] = sr; sini[off+8+n] = si;
        float nr = fmaf(wLr,sr, fmaf(-wLi,si, lr));
        float ni = fmaf(wLr,si, fmaf( wLi,sr, li));
        sr=nr; si=ni;
    }
}

// ---------------- fused per-depth kernel, MODE 0=first 1=mid 2=last ----------------
// thread = (chunk cc, channel ch); weights register-resident; one 32KB tile.
// P1 mix_d -> utile col | P2 scan+film+residual (own col, in place) | barrier
// P3 mix_{d+1}+local scan -> sloc   (MODE2: contract via shfl reduce)
template<int MODE>
__global__ __launch_bounds__(TPB) void k_mainT(
    const float* __restrict__ x, float* __restrict__ hbuf,
    const float* __restrict__ eW, const float* __restrict__ eb,
    const float* __restrict__ ab0,
    const float* __restrict__ linW_d, const float* __restrict__ linB_d,
    const float* __restrict__ linW_n, const float* __restrict__ linB_n,
    const float* __restrict__ pw_d, const float* __restrict__ pc2_d,
    const float* __restrict__ pw_n,
    const float* __restrict__ sini, float* __restrict__ sloc,
    const float* __restrict__ Dskip, const float* __restrict__ film,
    const float* __restrict__ resw,
    const float* __restrict__ cW, const float* __restrict__ cb,
    float* __restrict__ out)
{
    __shared__ float utile[CHB][LCq][Hq];   // 32 KB
    const int tid = threadIdx.x;
    const int cc = tid >> 5, ch = tid & 31;
    const int cg0 = blockIdx.x * CHB;
    const int b = cg0 >> 10;
    const int c = (cg0 & (NCq-1)) + cc;
    const size_t rec0 = ((size_t)b*Lq + (size_t)c*LCq)*Hq;   // float idx of this chunk's row 0
    const size_t xo0  = (size_t)b*Lq + (size_t)c*LCq;

    // ---- P1: mix_d -> own column of utile (weights in regs; rows broadcast from global)
    if (MODE == 0) {
        float al = ab0[ch], be = ab0[32+ch];
        #pragma unroll 4
        for (int j=0;j<LCq;j++){
            float xv = x[xo0 + j];
            float u = fmaf(xv, al, be);
            utile[cc][j][ch] = u>0.f?u:0.f;
        }
    } else {
        float W[Hq];
        #pragma unroll
        for (int k=0;k<8;k++) ((float4*)W)[k] = ((const float4*)(linW_d + ch*Hq))[k];
        float lb = linB_d[ch];
        #pragma unroll 2
        for (int j=0;j<LCq;j++){
            const float4* r4 = (const float4*)(hbuf + rec0 + (size_t)j*Hq);
            float a0=lb, a1=0.f, a2=0.f, a3=0.f;
            #pragma unroll
            for (int k=0;k<8;k++){
                float4 v = r4[k];
                a0 = fmaf(W[4*k+0], v.x, a0);
                a1 = fmaf(W[4*k+1], v.y, a1);
                a2 = fmaf(W[4*k+2], v.z, a2);
                a3 = fmaf(W[4*k+3], v.w, a3);
            }
            float u = (a0+a1)+(a2+a3);
            utile[cc][j][ch] = u>0.f?u:0.f;
        }
    }
    // no barrier: P2 reads only this thread's own column

    // ---- P2: seeded scan + FiLM + ReLU + residual, in place on own column
    {
        float wr[Nq],wi[Nq],cr[Nq],ci[Nq],sr[Nq],si[Nq];
        #pragma unroll
        for (int n=0;n<Nq;n++){
            wr[n]=pw_d[(ch*Nq+n)*2];  wi[n]=pw_d[(ch*Nq+n)*2+1];
            cr[n]=pc2_d[(ch*Nq+n)*2]; ci[n]=pc2_d[(ch*Nq+n)*2+1];
        }
        size_t sb = ((size_t)(b*NCq + c)*Hq + ch)*16;
        #pragma unroll
        for (int n=0;n<Nq;n++){ sr[n]=sini[sb+n]; si[n]=sini[sb+8+n]; }
        float D  = Dskip[ch];
        float gf = film[b*2*Hq + ch], bf = film[b*2*Hq + Hq + ch];
        float rw = resw[ch];
        float eWc = eW[ch], ebc = eb[ch];
        #pragma unroll 2
        for (int j=0;j<LCq;j++){
            float u = utile[cc][j][ch];
            float y = D*u;
            #pragma unroll
            for (int n=0;n<Nq;n++){
                float nr = fmaf(wr[n],sr[n], fmaf(-wi[n],si[n], u));
                float ni = fmaf(wr[n],si[n], wi[n]*sr[n]);
                sr[n]=nr; si[n]=ni;
                y = fmaf(cr[n],nr,y);
                y = fmaf(-ci[n],ni,y);
            }
            y = fmaf(y,gf,bf);
            y = y>0.f?y:0.f;
            float ho;
            if (MODE == 0) ho = fmaf(x[xo0+j], eWc, ebc);
            else           ho = hbuf[rec0 + (size_t)j*Hq + ch];
            float hn = fmaf(rw, ho, y);
            utile[cc][j][ch] = hn;
            if (MODE != 2) hbuf[rec0 + (size_t)j*Hq + ch] = hn;
        }
    }

    if (MODE == 2) {
        // contract + tanh + side-chain: own column * cW, shfl-reduce across 32 lanes
        float cw = cW[ch], cb0 = cb[0];
        #pragma unroll 2
        for (int j=0;j<LCq;j++){
            float val = cw * utile[cc][j][ch];
            val += __shfl_xor(val, 1);
            val += __shfl_xor(val, 2);
            val += __shfl_xor(val, 4);
            val += __shfl_xor(val, 8);
            val += __shfl_xor(val, 16);
            if (ch == 0) out[xo0 + j] = x[xo0 + j]*tanhf(val + cb0);
        }
        return;
    }

    __syncthreads();   // P3 reads rows written by other threads

    // ---- P3: mix_{d+1} (rows from LDS broadcast, W_n in regs) + local scan -> sloc
    {
        float W[Hq];
        #pragma unroll
        for (int k=0;k<8;k++) ((float4*)W)[k] = ((const float4*)(linW_n + ch*Hq))[k];
        float lb = linB_n[ch];
        float vr[Nq],vi[Nq],tr_[Nq],ti_[Nq];
        #pragma unroll
        for (int n=0;n<Nq;n++){
            vr[n]=pw_n[(ch*Nq+n)*2]; vi[n]=pw_n[(ch*Nq+n)*2+1];
            tr_[n]=0.f; ti_[n]=0.f;
        }
        #pragma unroll 2
        for (int j=0;j<LCq;j++){
            const float4* r4 = (const float4*)(&utile[cc][j][0]);
            float a0=lb, a1=0.f, a2=0.f, a3=0.f;
            #pragma unroll
            for (int k=0;k<8;k++){
                float4 v = r4[k];
                a0 = fmaf(W[4*k+0], v.x, a0);
                a1 = fmaf(W[4*k+1], v.y, a1);
                a2 = fmaf(W[4*k+2], v.z, a2);
                a3 = fmaf(W[4*k+3], v.w, a3);
            }
            float u = (a0+a1)+(a2+a3);
            u = u>0.f?u:0.f;
            #pragma unroll
            for (int n=0;n<Nq;n++){
                float nr = fmaf(vr[n],tr_[n], fmaf(-vi[n],ti_[n], u));
                float ni = fmaf(vr[n],ti_[n], vi[n]*tr_[n]);
                tr_[n]=nr; ti_[n]=ni;
            }
        }
        size_t sb = ((size_t)(b*NCq + c)*Hq + ch)*16;
        #pragma unroll
        for (int n=0;n<Nq;n++){ sloc[sb+n]=tr_[n]; sloc[sb+8+n]=ti_[n]; }
    }
}

// ---------------- diagnostic flag ----------------
__global__ void k_flag(float* __restrict__ out, int code) { out[0] = (float)code; }

extern "C" void kernel_launch(void* const* d_in, const int* in_sizes, int n_in,
                              void* d_out, int out_size, void* d_ws, size_t ws_size,
                              hipStream_t stream)
{
    const float* x    = (const float*)d_in[0];
    const float* prm  = (const float*)d_in[1];
    const float* W1   = (const float*)d_in[2];  const float* b1 = (const float*)d_in[3];
    const float* W2   = (const float*)d_in[4];  const float* b2 = (const float*)d_in[5];
    const float* W3   = (const float*)d_in[6];  const float* b3 = (const float*)d_in[7];
    const float* eW   = (const float*)d_in[8];  const float* eb = (const float*)d_in[9];
    const float* linW = (const float*)d_in[10]; const float* linB = (const float*)d_in[11];
    const float* log_dt = (const float*)d_in[12]; const float* logAre = (const float*)d_in[13];
    const float* Aim  = (const float*)d_in[14]; const float* Cre = (const float*)d_in[15];
    const float* Cim  = (const float*)d_in[16]; const float* Dskip = (const float*)d_in[17];
    const float* filmW= (const float*)d_in[18]; const float* filmB = (const float*)d_in[19];
    const float* resw = (const float*)d_in[20]; const float* cW = (const float*)d_in[21];
    const float* cb   = (const float*)d_in[22];

    float* sloc = (float*)d_ws;                                    // 4194304 f
    float* sini = sloc + (size_t)Bq*NCq*Hq*16;                     // 4194304 f
    float* pw   = sini + (size_t)Bq*NCq*Hq*16;                     // 2048 f
    float* pc2  = pw  + DEPq*Hq*Nq*2;                              // 2048 f
    float* pwL  = pc2 + DEPq*Hq*Nq*2;                              // 2048 f
    float* pwG  = pwL + DEPq*Hq*Nq*2;                              // 2048 f
    float* film = pwG + DEPq*Hq*Nq*2;                              // 2048 f
    float* ab0  = film + DEPq*Bq*2*Hq;                             // 64 f
    float* hbuf = ab0 + 64;                                        // 16777216 f
    float* out  = (float*)d_out;
    size_t ws_needed = (char*)(hbuf + (size_t)Bq*Lq*Hq) - (char*)d_ws;

    hipLaunchKernelGGL(k_cond_film, dim3(DEPq), dim3(512), 0, stream,
                       prm,W1,b1,W2,b2,W3,b3,filmW,filmB,film);
    hipLaunchKernelGGL(k_s4params, dim3(1), dim3(DEPq*Hq*Nq), 0, stream,
                       log_dt,logAre,Aim,Cre,Cim,pw,pc2,pwL,pwG);
    hipLaunchKernelGGL(k_premix, dim3(1), dim3(Hq), 0, stream, linW, linB, eW, eb, ab0);
    hipLaunchKernelGGL(k_first, dim3(Bq*NCq), dim3(256), 0, stream, x, ab0, pw, sloc);

    const int main_grid = Bq*NCq/CHB;   // 2048
    for (int d=0; d<DEPq; d++){
        hipLaunchKernelGGL(k_pass2, dim3(Bq*Hq), dim3(256), 0, stream,
                           sloc, pwL + d*Hq*Nq*2, pwG + d*Hq*Nq*2, sini);
        int dn = (d < DEPq-1) ? d+1 : d;
        if (d == 0) {
            hipLaunchKernelGGL((k_mainT<0>), dim3(main_grid), dim3(TPB), 0, stream,
                x, hbuf, eW, eb, ab0,
                linW + d*Hq*Hq, linB + d*Hq, linW + dn*Hq*Hq, linB + dn*Hq,
                pw + d*Hq*Nq*2, pc2 + d*Hq*Nq*2, pw + dn*Hq*Nq*2,
                sini, sloc, Dskip + d*Hq, film + d*Bq*2*Hq, resw + d*Hq,
                cW, cb, out);
        } else if (d < DEPq-1) {
            hipLaunchKernelGGL((k_mainT<1>), dim3(main_grid), dim3(TPB), 0, stream,
                x, hbuf, eW, eb, ab0,
                linW + d*Hq*Hq, linB + d*Hq, linW + dn*Hq*Hq, linB + dn*Hq,
                pw + d*Hq*Nq*2, pc2 + d*Hq*Nq*2, pw + dn*Hq*Nq*2,
                sini, sloc, Dskip + d*Hq, film + d*Bq*2*Hq, resw + d*Hq,
                cW, cb, out);
        } else {
            hipLaunchKernelGGL((k_mainT<2>), dim3(main_grid), dim3(TPB), 0, stream,
                x, hbuf, eW, eb, ab0,
                linW + d*Hq*Hq, linB + d*Hq, linW + dn*Hq*Hq, linB + dn*Hq,
                pw + d*Hq*Nq*2, pc2 + d*Hq*Nq*2, pw + dn*Hq*Nq*2,
                sini, sloc, Dskip + d*Hq, film + d*Bq*2*Hq, resw + d*Hq,
                cW, cb, out);
        }
    }

    static const int expected[23] = {
        Bq*Lq, Bq*2, 32, 16, 512, 32, 1024, 32, Hq, Hq,
        DEPq*Hq*Hq, DEPq*Hq, DEPq*Hq, DEPq*Hq*Nq, DEPq*Hq*Nq, DEPq*Hq*Nq, DEPq*Hq*Nq,
        DEPq*Hq, DEPq*2*Hq*32, DEPq*2*Hq, DEPq*Hq, Hq, 1
    };
    int code = 0;
    if (n_in != 23) code = 99;
    else { for (int i = 0; i < 23; i++) if (in_sizes[i] != expected[i]) { code = 100 + i; break; } }
    if (!code && ws_size < ws_needed) code = 200;
    if (code) hipLaunchKernelGGL(k_flag, dim3(1), dim3(1), 0, stream, out, code);
}